// Round 18
// baseline (365.846 us; speedup 1.0000x reference)
//
#include <hip/hip_runtime.h>
#include <hip/hip_bf16.h>

#define HH 224
#define WW 224

// d_out layout (floats): feats[32*128] | final_boxes[32*100*4] | final_scores[32*100] | keep[32*100]
#define OUT_FEATS  0
#define OUT_BOXES  4096
#define OUT_SCORES 16896
#define OUT_KEEP   20096

typedef __attribute__((ext_vector_type(8))) short short8;
typedef __attribute__((ext_vector_type(4))) float f32x4;
typedef __attribute__((ext_vector_type(4))) unsigned int u32x4;
typedef __attribute__((ext_vector_type(2))) unsigned int u32x2;

static __device__ __forceinline__ unsigned short f2bf(float f) {
    __hip_bfloat16 h = __float2bfloat16(f);
    return *(unsigned short*)&h;
}

static __device__ __forceinline__ void gload_lds16(const void* g, void* l) {
    __builtin_amdgcn_global_load_lds(
        (const __attribute__((address_space(1))) unsigned int*)g,
        (__attribute__((address_space(3))) unsigned int*)l, 16, 0, 0);
}

// ---------------- w2 (128,64,3,3) fp32 -> bf16 [tap][oc][ic] ----------------
__global__ void w2_convert(const float* __restrict__ w2, unsigned short* __restrict__ w2bf)
{
    int t = blockIdx.x * 256 + threadIdx.x;
    if (t >= 9 * 128 * 64) return;
    int tap = t >> 13;
    int rem = t & 8191;
    int oc = rem >> 6, ic = rem & 63;
    w2bf[t] = f2bf(w2[(oc * 64 + ic) * 9 + tap]);
}

// ---------------- w1 (64,3,3,3) fp32 -> bf16 [oc][k32], k=ic*9+dy*3+dx, pad 27..31=0 ----------------
__global__ void w1_convert(const float* __restrict__ w1, unsigned short* __restrict__ w1bf)
{
    int t = blockIdx.x * 256 + threadIdx.x;
    if (t >= 64 * 32) return;
    int oc = t >> 5, k = t & 31;
    unsigned short v = 0;
    if (k < 27) v = f2bf(w1[oc * 27 + k]);
    w1bf[t] = v;
}

// ================= v10: 4-blocks/CU variant (A/B test, batches 0..15) =================
// v7 structure (single 16KB tap buffer) + xpatch ALIASED onto it + launch_bounds(256,4)
// forcing the 128-reg class (acc 64 + arch <= 64, addresses rematerialized).
// LDS = 23040 (halo) + 16384 (wlds/xpatch) = 39424 B -> 4 blocks/CU = 16 waves (class-128).
__global__ __launch_bounds__(256, 4) void fused_conv_v10(const float* __restrict__ x,
                                                         const unsigned short* __restrict__ w1bf,
                                                         const float* __restrict__ b1,
                                                         const unsigned short* __restrict__ w2bf,
                                                         const float* __restrict__ b2,
                                                         float* __restrict__ partial,
                                                         int bbase)
{
    const int xt = blockIdx.x, yt = blockIdx.y, b = blockIdx.z + bbase;
    const int x0 = xt * 16, ty0 = yt * 8;
    const int tid = threadIdx.x;
    const int w = tid >> 6, lane = tid & 63;
    const int wm = w >> 1, wn = w & 1;     // conv2: px rows [wm*4,+4), oc [wn*64,+64)
    const int l15 = lane & 15, lq = lane >> 4;

    __shared__ char smem[39424];
    short* halo   = (short*)smem;               // [180 pos(10x18)][64 ic] XOR-swizzled, 23040 B
    char*  wlds   = smem + 23040;               // SINGLE tap weight buffer, 16384 B
    float* xpatch = (float*)(smem + 23040);     // ALIAS: xpatch used before wlds is first written

    // ---- stage x patch [3][12][20] (origin ty0-2, x0-2); zero tail for k>=27 ----
    for (int i = tid; i < 928; i += 256) {
        float v = 0.f;
        if (i < 720) {
            int ic = i / 240; int rem = i - ic * 240;
            int r = rem / 20, c = rem - r * 20;
            int gy = ty0 - 2 + r, gx = x0 - 2 + c;
            if (gy >= 0 && gy < HH && gx >= 0 && gx < WW)
                v = x[((b * 3 + ic) * HH + gy) * WW + gx];
        }
        xpatch[i] = v;
    }

    // conv1 constants (dead after phase 1)
    short8 aw[4];
#pragma unroll
    for (int f = 0; f < 4; f++)
        aw[f] = *(const short8*)(w1bf + (f * 16 + l15) * 32 + lq * 8);
    float bias1[4][4];
#pragma unroll
    for (int f = 0; f < 4; f++)
#pragma unroll
        for (int j = 0; j < 4; j++)
            bias1[f][j] = b1[f * 16 + lq * 4 + j];

    int koff[8];
#pragma unroll
    for (int j = 0; j < 8; j++) {
        int k = lq * 8 + j;
        int ic = (k >= 18) ? 2 : (k >= 9 ? 1 : 0);
        int t = k - ic * 9;
        int dy = (t >= 6) ? 2 : (t >= 3 ? 1 : 0);
        int dx = t - dy * 3;
        koff[j] = (k < 27) ? ((ic * 12 + dy) * 20 + dx) * 4 : 2880;  // zero tail at 2880+
    }
    __syncthreads();   // xpatch ready

    // ---- phase 1: conv1 -> halo (12 px-groups of 16 over 180 halo px) ----
    const char* xpb = (const char*)xpatch;
    for (int g = w; g < 12; g += 4) {
        int px0 = g * 16 + l15;
        int px = px0 > 179 ? 179 : px0;
        int row = (px * 456) >> 13;       // px/18, exact for px<324
        int col = px - row * 18;
        int rofs = row * 80 + col * 4;

        float pv[8];
#pragma unroll
        for (int j = 0; j < 8; j++)
            pv[j] = *(const float*)(xpb + (koff[j] + rofs));
        short8 bp;
        unsigned int* bpu = (unsigned int*)&bp;
#pragma unroll
        for (int jj = 0; jj < 4; jj++)
            bpu[jj] = (unsigned int)f2bf(pv[2 * jj]) | ((unsigned int)f2bf(pv[2 * jj + 1]) << 16);

        int gy = ty0 + row - 1, gx = x0 + col - 1;
        float vm = (gy >= 0 && gy < HH && gx >= 0 && gx < WW) ? 1.f : 0.f;  // SAME-pad mask
        bool wr = (px0 < 180);

#pragma unroll
        for (int f = 0; f < 4; f++) {
            f32x4 c = __builtin_amdgcn_mfma_f32_16x16x32_bf16(aw[f], bp,
                        (f32x4){0.f, 0.f, 0.f, 0.f}, 0, 0, 0);
            float v0 = fmaxf(c[0] + bias1[f][0], 0.f) * vm;
            float v1 = fmaxf(c[1] + bias1[f][1], 0.f) * vm;
            float v2 = fmaxf(c[2] + bias1[f][2], 0.f) * vm;
            float v3 = fmaxf(c[3] + bias1[f][3], 0.f) * vm;
            if (wr) {
                u32x2 pk;
                pk.x = (unsigned int)f2bf(v0) | ((unsigned int)f2bf(v1) << 16);
                pk.y = (unsigned int)f2bf(v2) | ((unsigned int)f2bf(v3) << 16);
                int byte = (px * 128 + f * 32 + lq * 8) ^ ((px & 7) << 4);
                *(u32x2*)((char*)halo + byte) = pk;
            }
        }
    }
    __syncthreads();   // conv1 done; xpatch DEAD -> wlds region free

    // ---- stage tap 0 into wlds ----
#pragma unroll
    for (int it = 0; it < 4; ++it) {
        int c = it * 256 + tid;
        gload_lds16((const char*)w2bf + ((c * 16) ^ (((c >> 3) & 7) << 4)),
                    wlds + c * 16);
    }
    __syncthreads();   // wlds(tap0) ready

    // ---- phase 2: conv2 K-loop, single-buffered weights; addresses rematerialized ----
    f32x4 acc[4][4];
#pragma unroll
    for (int mf = 0; mf < 4; mf++)
#pragma unroll
        for (int nf = 0; nf < 4; nf++)
            acc[mf][nf] = (f32x4){0.f, 0.f, 0.f, 0.f};

#pragma unroll
    for (int t = 0; t < 9; ++t) {
        const int dy = t / 3, dx = t % 3;
#pragma unroll
        for (int kk = 0; kk < 2; kk++) {
            short8 bfr[4];
#pragma unroll
            for (int nf = 0; nf < 4; nf++) {
                int oc = wn * 64 + nf * 16 + l15;
                int byte = (oc * 128 + kk * 64 + lq * 16) ^ ((oc & 7) << 4);
                bfr[nf] = *(const short8*)(wlds + byte);
            }
            short8 a[4];
#pragma unroll
            for (int mf = 0; mf < 4; mf++) {
                int pos = (wm * 4 + mf + dy) * 18 + l15 + dx;
                int byte = (pos * 128 + kk * 64 + lq * 16) ^ ((pos & 7) << 4);
                a[mf] = *(const short8*)((const char*)halo + byte);
            }
#pragma unroll
            for (int mf = 0; mf < 4; mf++)
#pragma unroll
                for (int nf = 0; nf < 4; nf++)
                    acc[mf][nf] = __builtin_amdgcn_mfma_f32_16x16x32_bf16(a[mf], bfr[nf], acc[mf][nf], 0, 0, 0);
        }
        __syncthreads();   // all reads of wlds(tap t) done
        if (t < 8) {
            const char* wsrc = (const char*)w2bf + (t + 1) * 16384;
#pragma unroll
            for (int it = 0; it < 4; ++it) {
                int c = it * 256 + tid;
                gload_lds16(wsrc + ((c * 16) ^ (((c >> 3) & 7) << 4)), wlds + c * 16);
            }
            __syncthreads();   // wlds(tap t+1) ready
        }
    }

    // ---- phase 3: bias + relu + px-sum -> partial ----
    float s[4];
#pragma unroll
    for (int nf = 0; nf < 4; nf++) {
        float bias = b2[wn * 64 + nf * 16 + l15];
        float v = 0.f;
#pragma unroll
        for (int mf = 0; mf < 4; mf++)
#pragma unroll
            for (int j = 0; j < 4; j++)
                v += fmaxf(acc[mf][nf][j] + bias, 0.f);
        v += __shfl_xor(v, 16, 64);
        v += __shfl_xor(v, 32, 64);
        s[nf] = v;
    }

    float* red = (float*)halo;
    if (lq == 0) {
#pragma unroll
        for (int nf = 0; nf < 4; nf++)
            red[((wm * 2 + wn) * 4 + nf) * 16 + l15] = s[nf];
    }
    __syncthreads();
    if (tid < 128) {
        int oc = tid;
        int wn2 = oc >> 6, nf2 = (oc >> 4) & 3, c16 = oc & 15;
        float tot = red[((0 * 2 + wn2) * 4 + nf2) * 16 + c16] +
                    red[((1 * 2 + wn2) * 4 + nf2) * 16 + c16];
        int tile = yt * 14 + xt;
        partial[((size_t)b * 128 + oc) * 392 + tile] = tot;
    }
}

// ================= v5 (R13 best, 283us): batches 16..31 =================
__global__ __launch_bounds__(256) void fused_conv_v5(const float* __restrict__ x,
                                                     const unsigned short* __restrict__ w1bf,
                                                     const float* __restrict__ b1,
                                                     const unsigned short* __restrict__ w2bf,
                                                     const float* __restrict__ b2,
                                                     float* __restrict__ partial,
                                                     int bbase)
{
    const int xt = blockIdx.x, yt = blockIdx.y, b = blockIdx.z + bbase;
    const int x0 = xt * 16, ty0 = yt * 8;
    const int tid = threadIdx.x;
    const int w = tid >> 6, lane = tid & 63;
    const int wm = w >> 1, wn = w & 1;
    const int l15 = lane & 15, lq = lane >> 4;

    __shared__ char smem[55808];
    short* halo   = (short*)smem;
    char*  wlds0 = smem + 23040;
    char*  wlds1 = smem + 23040 + 16384;
    float* xpatch = (float*)wlds1;

#pragma unroll
    for (int it = 0; it < 4; ++it) {
        int cbase = it * 256 + w * 64;
        int c = cbase + lane;
        int src = (c * 16) ^ (((c >> 3) & 7) << 4);
        gload_lds16((const char*)w2bf + src, wlds0 + cbase * 16);
    }

    for (int i = tid; i < 928; i += 256) {
        float v = 0.f;
        if (i < 720) {
            int ic = i / 240; int rem = i - ic * 240;
            int r = rem / 20, c = rem - r * 20;
            int gy = ty0 - 2 + r, gx = x0 - 2 + c;
            if (gy >= 0 && gy < HH && gx >= 0 && gx < WW)
                v = x[((b * 3 + ic) * HH + gy) * WW + gx];
        }
        xpatch[i] = v;
    }

    short8 aw[4];
#pragma unroll
    for (int f = 0; f < 4; f++)
        aw[f] = *(const short8*)(w1bf + (f * 16 + l15) * 32 + lq * 8);
    float bias1[4][4];
#pragma unroll
    for (int f = 0; f < 4; f++)
#pragma unroll
        for (int j = 0; j < 4; j++)
            bias1[f][j] = b1[f * 16 + lq * 4 + j];

    int koff[8];
#pragma unroll
    for (int j = 0; j < 8; j++) {
        int k = lq * 8 + j;
        int ic = (k >= 18) ? 2 : (k >= 9 ? 1 : 0);
        int t = k - ic * 9;
        int dy = (t >= 6) ? 2 : (t >= 3 ? 1 : 0);
        int dx = t - dy * 3;
        koff[j] = (k < 27) ? ((ic * 12 + dy) * 20 + dx) * 4 : 2880;
    }
    __syncthreads();

    const char* xpb = (const char*)xpatch;
    for (int g = w; g < 12; g += 4) {
        int px0 = g * 16 + l15;
        int px = px0 > 179 ? 179 : px0;
        int row = (px * 456) >> 13;
        int col = px - row * 18;
        int rofs = row * 80 + col * 4;

        float pv[8];
#pragma unroll
        for (int j = 0; j < 8; j++)
            pv[j] = *(const float*)(xpb + (koff[j] + rofs));
        short8 bp;
        unsigned int* bpu = (unsigned int*)&bp;
#pragma unroll
        for (int jj = 0; jj < 4; jj++)
            bpu[jj] = (unsigned int)f2bf(pv[2 * jj]) | ((unsigned int)f2bf(pv[2 * jj + 1]) << 16);

        int gy = ty0 + row - 1, gx = x0 + col - 1;
        float vm = (gy >= 0 && gy < HH && gx >= 0 && gx < WW) ? 1.f : 0.f;
        bool wr = (px0 < 180);

#pragma unroll
        for (int f = 0; f < 4; f++) {
            f32x4 c = __builtin_amdgcn_mfma_f32_16x16x32_bf16(aw[f], bp,
                        (f32x4){0.f, 0.f, 0.f, 0.f}, 0, 0, 0);
            float v0 = fmaxf(c[0] + bias1[f][0], 0.f) * vm;
            float v1 = fmaxf(c[1] + bias1[f][1], 0.f) * vm;
            float v2 = fmaxf(c[2] + bias1[f][2], 0.f) * vm;
            float v3 = fmaxf(c[3] + bias1[f][3], 0.f) * vm;
            if (wr) {
                u32x2 pk;
                pk.x = (unsigned int)f2bf(v0) | ((unsigned int)f2bf(v1) << 16);
                pk.y = (unsigned int)f2bf(v2) | ((unsigned int)f2bf(v3) << 16);
                int byte = (px * 128 + f * 32 + lq * 8) ^ ((px & 7) << 4);
                *(u32x2*)((char*)halo + byte) = pk;
            }
        }
    }
    __syncthreads();

    f32x4 acc[4][4];
#pragma unroll
    for (int mf = 0; mf < 4; mf++)
#pragma unroll
        for (int nf = 0; nf < 4; nf++)
            acc[mf][nf] = (f32x4){0.f, 0.f, 0.f, 0.f};

#pragma unroll
    for (int t = 0; t < 9; ++t) {
        if (t < 8) {
            char* wdst = ((t + 1) & 1) ? wlds1 : wlds0;
#pragma unroll
            for (int it = 0; it < 4; ++it) {
                int cbase = it * 256 + w * 64;
                int c = cbase + lane;
                int src = (c * 16) ^ (((c >> 3) & 7) << 4);
                gload_lds16((const char*)w2bf + (t + 1) * 16384 + src, wdst + cbase * 16);
            }
        }
        const int dy = t / 3, dx = t % 3;
        const char* wbuf = (t & 1) ? wlds1 : wlds0;

#pragma unroll
        for (int kk = 0; kk < 2; kk++) {
            short8 bfr[4];
#pragma unroll
            for (int nf = 0; nf < 4; nf++) {
                int oc = wn * 64 + nf * 16 + l15;
                int byte = (oc * 128 + kk * 64 + lq * 16) ^ ((oc & 7) << 4);
                bfr[nf] = *(const short8*)(wbuf + byte);
            }
            short8 a[4];
#pragma unroll
            for (int mf = 0; mf < 4; mf++) {
                int pos = (wm * 4 + mf + dy) * 18 + (l15 + dx);
                int byte = (pos * 128 + kk * 64 + lq * 16) ^ ((pos & 7) << 4);
                a[mf] = *(const short8*)((const char*)halo + byte);
            }
#pragma unroll
            for (int mf = 0; mf < 4; mf++)
#pragma unroll
                for (int nf = 0; nf < 4; nf++)
                    acc[mf][nf] = __builtin_amdgcn_mfma_f32_16x16x32_bf16(a[mf], bfr[nf], acc[mf][nf], 0, 0, 0);
        }
        __syncthreads();
    }

    float s[4];
#pragma unroll
    for (int nf = 0; nf < 4; nf++) {
        float bias = b2[wn * 64 + nf * 16 + l15];
        float v = 0.f;
#pragma unroll
        for (int mf = 0; mf < 4; mf++)
#pragma unroll
            for (int j = 0; j < 4; j++)
                v += fmaxf(acc[mf][nf][j] + bias, 0.f);
        v += __shfl_xor(v, 16, 64);
        v += __shfl_xor(v, 32, 64);
        s[nf] = v;
    }

    float* red = (float*)halo;
    if (lq == 0) {
#pragma unroll
        for (int nf = 0; nf < 4; nf++)
            red[((wm * 2 + wn) * 4 + nf) * 16 + l15] = s[nf];
    }
    __syncthreads();
    if (tid < 128) {
        int oc = tid;
        int wn2 = oc >> 6, nf2 = (oc >> 4) & 3, c16 = oc & 15;
        float tot = red[((0 * 2 + wn2) * 4 + nf2) * 16 + c16] +
                    red[((1 * 2 + wn2) * 4 + nf2) * 16 + c16];
        int tile = yt * 14 + xt;
        partial[((size_t)b * 128 + oc) * 392 + tile] = tot;
    }
}

// ---------------- feats: sum 392 tile-partials -> mean ----------------
__global__ void feats_reduce(const float* __restrict__ partial, float* __restrict__ out)
{
    int t = blockIdx.x;           // 0..4095 = b*128+oc
    int lane = threadIdx.x;       // 64
    float s = 0.f;
    for (int k = lane; k < 392; k += 64) s += partial[(size_t)t * 392 + k];
#pragma unroll
    for (int m = 32; m >= 1; m >>= 1) s += __shfl_xor(s, m, 64);
    if (lane == 0) out[t] = s * (1.f / 50176.f);
}

// ---------------- NMS: one block per batch (exact reference semantics) ----------------
__global__ __launch_bounds__(128) void nms_kernel(const float* __restrict__ boxes,
                                                  const float* __restrict__ scores,
                                                  float* __restrict__ out)
{
    const int b = blockIdx.x;
    const int tid = threadIdx.x;
    __shared__ float rs[100];
    __shared__ float bx1[100], by1[100], bx2[100], by2[100];
    __shared__ float ss[100], sx1[100], sy1[100], sx2[100], sy2[100], sarea[100];
    __shared__ int keep_s[100];

    if (tid < 100) {
        rs[tid] = scores[b * 100 + tid];
        bx1[tid] = boxes[(b * 100 + tid) * 4 + 0];
        by1[tid] = boxes[(b * 100 + tid) * 4 + 1];
        bx2[tid] = boxes[(b * 100 + tid) * 4 + 2];
        by2[tid] = boxes[(b * 100 + tid) * 4 + 3];
    }
    __syncthreads();
    if (tid < 100) {
        float s = rs[tid];
        int r = 0;
        for (int j = 0; j < 100; j++) {
            float sj = rs[j];
            r += (sj > s) || (sj == s && j < tid);  // stable descending rank
        }
        ss[r] = s; sx1[r] = bx1[tid]; sy1[r] = by1[tid];
        sx2[r] = bx2[tid]; sy2[r] = by2[tid];
        keep_s[tid] = 1;
    }
    __syncthreads();
    if (tid < 100)
        sarea[tid] = fmaxf(sx2[tid] - sx1[tid], 0.f) * fmaxf(sy2[tid] - sy1[tid], 0.f);
    __syncthreads();

    for (int i = 0; i < 99; i++) {
        if (keep_s[i] && tid > i && tid < 100) {
            float xx1 = fmaxf(sx1[i], sx1[tid]);
            float yy1 = fmaxf(sy1[i], sy1[tid]);
            float xx2 = fminf(sx2[i], sx2[tid]);
            float yy2 = fminf(sy2[i], sy2[tid]);
            float inter = fmaxf(xx2 - xx1, 0.f) * fmaxf(yy2 - yy1, 0.f);
            float iou = inter / (sarea[i] + sarea[tid] - inter + 1e-9f);
            if (iou > 0.5f) keep_s[tid] = 0;
        }
        __syncthreads();
    }

    if (tid < 100) {
        int k = keep_s[tid];
        int gi = b * 100 + tid;
        out[OUT_BOXES + gi * 4 + 0] = k ? sx1[tid] : 0.f;
        out[OUT_BOXES + gi * 4 + 1] = k ? sy1[tid] : 0.f;
        out[OUT_BOXES + gi * 4 + 2] = k ? sx2[tid] : 0.f;
        out[OUT_BOXES + gi * 4 + 3] = k ? sy2[tid] : 0.f;
        out[OUT_SCORES + gi] = k ? ss[tid] : 0.f;
        out[OUT_KEEP + gi] = k ? 1.f : 0.f;
    }
}

extern "C" void kernel_launch(void* const* d_in, const int* in_sizes, int n_in,
                              void* d_out, int out_size, void* d_ws, size_t ws_size,
                              hipStream_t stream)
{
    const float* x      = (const float*)d_in[0];
    const float* boxes  = (const float*)d_in[1];
    const float* scores = (const float*)d_in[2];
    const float* w1     = (const float*)d_in[3];
    const float* b1     = (const float*)d_in[4];
    const float* w2     = (const float*)d_in[5];
    const float* b2     = (const float*)d_in[6];
    float* out = (float*)d_out;

    // ws: w2bf (147 KB) | w1bf (4 KB) | partial (6.4 MB) — no h1 buffer
    char* wsb = (char*)d_ws;
    unsigned short* w2bf = (unsigned short*)wsb;
    unsigned short* w1bf = (unsigned short*)(wsb + 9 * 128 * 64 * 2);
    float*          partial = (float*)(wsb + 9 * 128 * 64 * 2 + 64 * 32 * 2);

    w2_convert<<<(9 * 128 * 64 + 255) / 256, 256, 0, stream>>>(w2, w2bf);
    w1_convert<<<8, 256, 0, stream>>>(w1, w1bf);

    // within-probe A/B: v10 (4-blocks/CU candidate) on batches 0..15,
    // v5 (proven best) on batches 16..31. rocprof separates the dispatches.
    fused_conv_v10<<<dim3(14, 28, 16), 256, 0, stream>>>(x, w1bf, b1, w2bf, b2, partial, 0);
    fused_conv_v5 <<<dim3(14, 28, 16), 256, 0, stream>>>(x, w1bf, b1, w2bf, b2, partial, 16);

    feats_reduce<<<4096, 64, 0, stream>>>(partial, out + OUT_FEATS);
    nms_kernel<<<32, 128, 0, stream>>>(boxes, scores, out);
}

// Round 19
// 282.587 us; speedup vs baseline: 1.2946x; 1.2946x over previous
//
#include <hip/hip_runtime.h>
#include <hip/hip_bf16.h>

#define HH 224
#define WW 224

// d_out layout (floats): feats[32*128] | final_boxes[32*100*4] | final_scores[32*100] | keep[32*100]
#define OUT_FEATS  0
#define OUT_BOXES  4096
#define OUT_SCORES 16896
#define OUT_KEEP   20096

typedef __attribute__((ext_vector_type(8))) short short8;
typedef __attribute__((ext_vector_type(4))) float f32x4;
typedef __attribute__((ext_vector_type(4))) unsigned int u32x4;
typedef __attribute__((ext_vector_type(2))) unsigned int u32x2;

static __device__ __forceinline__ unsigned short f2bf(float f) {
    __hip_bfloat16 h = __float2bfloat16(f);
    return *(unsigned short*)&h;
}

static __device__ __forceinline__ void gload_lds16(const void* g, void* l) {
    __builtin_amdgcn_global_load_lds(
        (const __attribute__((address_space(1))) unsigned int*)g,
        (__attribute__((address_space(3))) unsigned int*)l, 16, 0, 0);
}

// ---------------- w2 (128,64,3,3) fp32 -> bf16 [tap][oc][ic] ----------------
__global__ void w2_convert(const float* __restrict__ w2, unsigned short* __restrict__ w2bf)
{
    int t = blockIdx.x * 256 + threadIdx.x;
    if (t >= 9 * 128 * 64) return;
    int tap = t >> 13;
    int rem = t & 8191;
    int oc = rem >> 6, ic = rem & 63;
    w2bf[t] = f2bf(w2[(oc * 64 + ic) * 9 + tap]);
}

// ---------------- w1 (64,3,3,3) fp32 -> bf16 [oc][k32], k=ic*9+dy*3+dx, pad 27..31=0 ----------------
__global__ void w1_convert(const float* __restrict__ w1, unsigned short* __restrict__ w1bf)
{
    int t = blockIdx.x * 256 + threadIdx.x;
    if (t >= 64 * 32) return;
    int oc = t >> 5, k = t & 31;
    unsigned short v = 0;
    if (k < 27) v = f2bf(w1[oc * 27 + k]);
    w1bf[t] = v;
}

// ================= FUSED conv1+conv2 per 8x16 output tile (v5 — best proven, R13) =================
// 256 thr = 4 waves (1 wave/SIMD each), grid (14,28,32). TWO blocks co-reside per CU
// (register class 256: 88 arch + 64 acc = 152 -> 2 waves/SIMD; LDS 55808 x2 <= 163840).
// Wave (wm 0..1, wn 0..1): px rows [wm*4,+4) x 16 cols (M=4), oc [wn*64,+64) (N=4).
// Weight LDS double-buffer staged per tap via global_load_lds; 1 barrier/tap.
// This is the 2-barrier-per-K-step structural plateau (MfmaUtil ~39%); class-128
// occupancy (4 blk/CU) spills transients (R18 A/B: 347MB scratch), pipelined-vmcnt
// (R16) and barrier-free (R17) variants are null at this tile geometry.
__global__ __launch_bounds__(256) void fused_conv_kernel(const float* __restrict__ x,
                                                         const unsigned short* __restrict__ w1bf,
                                                         const float* __restrict__ b1,
                                                         const unsigned short* __restrict__ w2bf,
                                                         const float* __restrict__ b2,
                                                         float* __restrict__ partial)
{
    const int xt = blockIdx.x, yt = blockIdx.y, b = blockIdx.z;
    const int x0 = xt * 16, ty0 = yt * 8;
    const int tid = threadIdx.x;
    const int w = tid >> 6, lane = tid & 63;
    const int wm = w >> 1, wn = w & 1;     // conv2: px rows [wm*4,+4), oc [wn*64,+64)
    const int l15 = lane & 15, lq = lane >> 4;

    __shared__ char smem[55808];
    short* halo   = (short*)smem;               // [180 pos(10x18)][64 ic] XOR-swizzled, 23040 B
    char*  wlds0 = smem + 23040;                // tap dbuf slot 0, 16384 B
    char*  wlds1 = smem + 23040 + 16384;        // tap dbuf slot 1, 16384 B
    float* xpatch = (float*)wlds1;              // ALIAS: [3][12][20]=720 + zero tail (928 floats)

    // ---- phase 0a: stage tap-0 weights into wlds0 (async; drained by first barrier) ----
#pragma unroll
    for (int it = 0; it < 4; ++it) {
        int cbase = it * 256 + w * 64;
        int c = cbase + lane;
        int src = (c * 16) ^ (((c >> 3) & 7) << 4);
        gload_lds16((const char*)w2bf + src, wlds0 + cbase * 16);
    }

    // ---- phase 0b: stage x patch [3][12][20] (origin ty0-2, x0-2); zero tail for k>=27 ----
    for (int i = tid; i < 928; i += 256) {
        float v = 0.f;
        if (i < 720) {
            int ic = i / 240; int rem = i - ic * 240;
            int r = rem / 20, c = rem - r * 20;
            int gy = ty0 - 2 + r, gx = x0 - 2 + c;
            if (gy >= 0 && gy < HH && gx >= 0 && gx < WW)
                v = x[((b * 3 + ic) * HH + gy) * WW + gx];
        }
        xpatch[i] = v;
    }

    // conv1 constants (dead after phase 1)
    short8 aw[4];
#pragma unroll
    for (int f = 0; f < 4; f++)
        aw[f] = *(const short8*)(w1bf + (f * 16 + l15) * 32 + lq * 8);
    float bias1[4][4];
#pragma unroll
    for (int f = 0; f < 4; f++)
#pragma unroll
        for (int j = 0; j < 4; j++)
            bias1[f][j] = b1[f * 16 + lq * 4 + j];

    int koff[8];
#pragma unroll
    for (int j = 0; j < 8; j++) {
        int k = lq * 8 + j;
        int ic = (k >= 18) ? 2 : (k >= 9 ? 1 : 0);
        int t = k - ic * 9;
        int dy = (t >= 6) ? 2 : (t >= 3 ? 1 : 0);
        int dx = t - dy * 3;
        koff[j] = (k < 27) ? ((ic * 12 + dy) * 20 + dx) * 4 : 2880;  // zero tail at 2880+
    }
    __syncthreads();   // xpatch + wlds0 ready

    // ---- phase 1: conv1 -> halo (12 px-groups of 16 over 180 halo px) ----
    const char* xpb = (const char*)xpatch;
    for (int g = w; g < 12; g += 4) {
        int px0 = g * 16 + l15;
        int px = px0 > 179 ? 179 : px0;
        int row = (px * 456) >> 13;       // px/18, exact for px<324
        int col = px - row * 18;
        int rofs = row * 80 + col * 4;

        float pv[8];
#pragma unroll
        for (int j = 0; j < 8; j++)
            pv[j] = *(const float*)(xpb + (koff[j] + rofs));
        short8 bp;
        unsigned int* bpu = (unsigned int*)&bp;
#pragma unroll
        for (int jj = 0; jj < 4; jj++)
            bpu[jj] = (unsigned int)f2bf(pv[2 * jj]) | ((unsigned int)f2bf(pv[2 * jj + 1]) << 16);

        int gy = ty0 + row - 1, gx = x0 + col - 1;
        float vm = (gy >= 0 && gy < HH && gx >= 0 && gx < WW) ? 1.f : 0.f;  // SAME-pad mask
        bool wr = (px0 < 180);

#pragma unroll
        for (int f = 0; f < 4; f++) {
            f32x4 c = __builtin_amdgcn_mfma_f32_16x16x32_bf16(aw[f], bp,
                        (f32x4){0.f, 0.f, 0.f, 0.f}, 0, 0, 0);
            float v0 = fmaxf(c[0] + bias1[f][0], 0.f) * vm;
            float v1 = fmaxf(c[1] + bias1[f][1], 0.f) * vm;
            float v2 = fmaxf(c[2] + bias1[f][2], 0.f) * vm;
            float v3 = fmaxf(c[3] + bias1[f][3], 0.f) * vm;
            if (wr) {
                u32x2 pk;
                pk.x = (unsigned int)f2bf(v0) | ((unsigned int)f2bf(v1) << 16);
                pk.y = (unsigned int)f2bf(v2) | ((unsigned int)f2bf(v3) << 16);
                int byte = (px * 128 + f * 32 + lq * 8) ^ ((px & 7) << 4);
                *(u32x2*)((char*)halo + byte) = pk;
            }
        }
    }
    __syncthreads();   // halo ready; xpatch now DEAD -> wlds1 alias becomes free

    // ---- phase 2: conv2 (M4N4, weights from LDS dbuf, per-tap stage) ----
    f32x4 acc[4][4];
#pragma unroll
    for (int mf = 0; mf < 4; mf++)
#pragma unroll
        for (int nf = 0; nf < 4; nf++)
            acc[mf][nf] = (f32x4){0.f, 0.f, 0.f, 0.f};

#pragma unroll
    for (int t = 0; t < 9; ++t) {
        if (t < 8) {
            char* wdst = ((t + 1) & 1) ? wlds1 : wlds0;
#pragma unroll
            for (int it = 0; it < 4; ++it) {
                int cbase = it * 256 + w * 64;
                int c = cbase + lane;
                int src = (c * 16) ^ (((c >> 3) & 7) << 4);
                gload_lds16((const char*)w2bf + (t + 1) * 16384 + src, wdst + cbase * 16);
            }
        }
        const int dy = t / 3, dx = t % 3;
        const char* wbuf = (t & 1) ? wlds1 : wlds0;

#pragma unroll
        for (int kk = 0; kk < 2; kk++) {
            short8 bfr[4];
#pragma unroll
            for (int nf = 0; nf < 4; nf++) {
                int oc = wn * 64 + nf * 16 + l15;
                int byte = (oc * 128 + kk * 64 + lq * 16) ^ ((oc & 7) << 4);
                bfr[nf] = *(const short8*)(wbuf + byte);
            }
            short8 a[4];
#pragma unroll
            for (int mf = 0; mf < 4; mf++) {
                int pos = (wm * 4 + mf + dy) * 18 + (l15 + dx);
                int byte = (pos * 128 + kk * 64 + lq * 16) ^ ((pos & 7) << 4);
                a[mf] = *(const short8*)((const char*)halo + byte);
            }
#pragma unroll
            for (int mf = 0; mf < 4; mf++)
#pragma unroll
                for (int nf = 0; nf < 4; nf++)
                    acc[mf][nf] = __builtin_amdgcn_mfma_f32_16x16x32_bf16(a[mf], bfr[nf], acc[mf][nf], 0, 0, 0);
        }
        __syncthreads();   // drains stage(t+1); publishes the other wlds slot
    }

    // ---- phase 3: bias + relu + px-sum -> partial ----
    float s[4];
#pragma unroll
    for (int nf = 0; nf < 4; nf++) {
        float bias = b2[wn * 64 + nf * 16 + l15];
        float v = 0.f;
#pragma unroll
        for (int mf = 0; mf < 4; mf++)
#pragma unroll
            for (int j = 0; j < 4; j++)
                v += fmaxf(acc[mf][nf][j] + bias, 0.f);
        v += __shfl_xor(v, 16, 64);
        v += __shfl_xor(v, 32, 64);
        s[nf] = v;
    }

    float* red = (float*)halo;     // halo reads all complete (final K-loop barrier)
    if (lq == 0) {
#pragma unroll
        for (int nf = 0; nf < 4; nf++)
            red[((wm * 2 + wn) * 4 + nf) * 16 + l15] = s[nf];
    }
    __syncthreads();
    if (tid < 128) {
        int oc = tid;
        int wn2 = oc >> 6, nf2 = (oc >> 4) & 3, c16 = oc & 15;
        float tot = red[((0 * 2 + wn2) * 4 + nf2) * 16 + c16] +
                    red[((1 * 2 + wn2) * 4 + nf2) * 16 + c16];
        int tile = yt * 14 + xt;
        partial[((size_t)b * 128 + oc) * 392 + tile] = tot;
    }
}

// ---------------- feats: sum 392 tile-partials -> mean ----------------
__global__ void feats_reduce(const float* __restrict__ partial, float* __restrict__ out)
{
    int t = blockIdx.x;           // 0..4095 = b*128+oc
    int lane = threadIdx.x;       // 64
    float s = 0.f;
    for (int k = lane; k < 392; k += 64) s += partial[(size_t)t * 392 + k];
#pragma unroll
    for (int m = 32; m >= 1; m >>= 1) s += __shfl_xor(s, m, 64);
    if (lane == 0) out[t] = s * (1.f / 50176.f);
}

// ---------------- NMS: one block per batch (exact reference semantics) ----------------
__global__ __launch_bounds__(128) void nms_kernel(const float* __restrict__ boxes,
                                                  const float* __restrict__ scores,
                                                  float* __restrict__ out)
{
    const int b = blockIdx.x;
    const int tid = threadIdx.x;
    __shared__ float rs[100];
    __shared__ float bx1[100], by1[100], bx2[100], by2[100];
    __shared__ float ss[100], sx1[100], sy1[100], sx2[100], sy2[100], sarea[100];
    __shared__ int keep_s[100];

    if (tid < 100) {
        rs[tid] = scores[b * 100 + tid];
        bx1[tid] = boxes[(b * 100 + tid) * 4 + 0];
        by1[tid] = boxes[(b * 100 + tid) * 4 + 1];
        bx2[tid] = boxes[(b * 100 + tid) * 4 + 2];
        by2[tid] = boxes[(b * 100 + tid) * 4 + 3];
    }
    __syncthreads();
    if (tid < 100) {
        float s = rs[tid];
        int r = 0;
        for (int j = 0; j < 100; j++) {
            float sj = rs[j];
            r += (sj > s) || (sj == s && j < tid);  // stable descending rank
        }
        ss[r] = s; sx1[r] = bx1[tid]; sy1[r] = by1[tid];
        sx2[r] = bx2[tid]; sy2[r] = by2[tid];
        keep_s[tid] = 1;
    }
    __syncthreads();
    if (tid < 100)
        sarea[tid] = fmaxf(sx2[tid] - sx1[tid], 0.f) * fmaxf(sy2[tid] - sy1[tid], 0.f);
    __syncthreads();

    for (int i = 0; i < 99; i++) {
        if (keep_s[i] && tid > i && tid < 100) {
            float xx1 = fmaxf(sx1[i], sx1[tid]);
            float yy1 = fmaxf(sy1[i], sy1[tid]);
            float xx2 = fminf(sx2[i], sx2[tid]);
            float yy2 = fminf(sy2[i], sy2[tid]);
            float inter = fmaxf(xx2 - xx1, 0.f) * fmaxf(yy2 - yy1, 0.f);
            float iou = inter / (sarea[i] + sarea[tid] - inter + 1e-9f);
            if (iou > 0.5f) keep_s[tid] = 0;
        }
        __syncthreads();
    }

    if (tid < 100) {
        int k = keep_s[tid];
        int gi = b * 100 + tid;
        out[OUT_BOXES + gi * 4 + 0] = k ? sx1[tid] : 0.f;
        out[OUT_BOXES + gi * 4 + 1] = k ? sy1[tid] : 0.f;
        out[OUT_BOXES + gi * 4 + 2] = k ? sx2[tid] : 0.f;
        out[OUT_BOXES + gi * 4 + 3] = k ? sy2[tid] : 0.f;
        out[OUT_SCORES + gi] = k ? ss[tid] : 0.f;
        out[OUT_KEEP + gi] = k ? 1.f : 0.f;
    }
}

extern "C" void kernel_launch(void* const* d_in, const int* in_sizes, int n_in,
                              void* d_out, int out_size, void* d_ws, size_t ws_size,
                              hipStream_t stream)
{
    const float* x      = (const float*)d_in[0];
    const float* boxes  = (const float*)d_in[1];
    const float* scores = (const float*)d_in[2];
    const float* w1     = (const float*)d_in[3];
    const float* b1     = (const float*)d_in[4];
    const float* w2     = (const float*)d_in[5];
    const float* b2     = (const float*)d_in[6];
    float* out = (float*)d_out;

    // ws: w2bf (147 KB) | w1bf (4 KB) | partial (6.4 MB) — no h1 buffer
    char* wsb = (char*)d_ws;
    unsigned short* w2bf = (unsigned short*)wsb;
    unsigned short* w1bf = (unsigned short*)(wsb + 9 * 128 * 64 * 2);
    float*          partial = (float*)(wsb + 9 * 128 * 64 * 2 + 64 * 32 * 2);

    w2_convert<<<(9 * 128 * 64 + 255) / 256, 256, 0, stream>>>(w2, w2bf);
    w1_convert<<<8, 256, 0, stream>>>(w1, w1bf);

    fused_conv_kernel<<<dim3(14, 28, 32), 256, 0, stream>>>(x, w1bf, b1, w2bf, b2, partial);

    feats_reduce<<<4096, 64, 0, stream>>>(partial, out + OUT_FEATS);
    nms_kernel<<<32, 128, 0, stream>>>(boxes, scores, out);
}

// Round 20
// 267.906 us; speedup vs baseline: 1.3656x; 1.0548x over previous
//
#include <hip/hip_runtime.h>
#include <hip/hip_bf16.h>

#define HH 224
#define WW 224

// d_out layout (floats): feats[32*128] | final_boxes[32*100*4] | final_scores[32*100] | keep[32*100]
#define OUT_FEATS  0
#define OUT_BOXES  4096
#define OUT_SCORES 16896
#define OUT_KEEP   20096

typedef __attribute__((ext_vector_type(8))) short short8;
typedef __attribute__((ext_vector_type(4))) float f32x4;
typedef __attribute__((ext_vector_type(16))) float f32x16;
typedef __attribute__((ext_vector_type(4))) unsigned int u32x4;
typedef __attribute__((ext_vector_type(2))) unsigned int u32x2;

static __device__ __forceinline__ unsigned short f2bf(float f) {
    __hip_bfloat16 h = __float2bfloat16(f);
    return *(unsigned short*)&h;
}

static __device__ __forceinline__ void gload_lds16(const void* g, void* l) {
    __builtin_amdgcn_global_load_lds(
        (const __attribute__((address_space(1))) unsigned int*)g,
        (__attribute__((address_space(3))) unsigned int*)l, 16, 0, 0);
}

// ---------------- w2 (128,64,3,3) fp32 -> bf16 [tap][oc][ic] ----------------
__global__ void w2_convert(const float* __restrict__ w2, unsigned short* __restrict__ w2bf)
{
    int t = blockIdx.x * 256 + threadIdx.x;
    if (t >= 9 * 128 * 64) return;
    int tap = t >> 13;
    int rem = t & 8191;
    int oc = rem >> 6, ic = rem & 63;
    w2bf[t] = f2bf(w2[(oc * 64 + ic) * 9 + tap]);
}

// ---------------- w1 (64,3,3,3) fp32 -> bf16 [oc][k32], k=ic*9+dy*3+dx, pad 27..31=0 ----------------
__global__ void w1_convert(const float* __restrict__ w1, unsigned short* __restrict__ w1bf)
{
    int t = blockIdx.x * 256 + threadIdx.x;
    if (t >= 64 * 32) return;
    int oc = t >> 5, k = t & 31;
    unsigned short v = 0;
    if (k < 27) v = f2bf(w1[oc * 27 + k]);
    w1bf[t] = v;
}

// ================= FUSED conv1+conv2 per 16x16 output tile (v11: 32x32 MFMA, acc=128) =================
// 256 thr = 4 waves, grid (14,14,32). 2 blocks/CU (class-256: acc 128 AGPR + arch <=128;
// LDS 74240 x2 <= 163840). Wave (wp=w>>1, wn=w&1): 128 px (rows [wp*8,+8) x 16 cols,
// 4x 32-row frags) x 64 oc (2x 32-col frags) via v_mfma_f32_32x32x16_bf16.
// Traffic tier: 43690 FLOP per LDS read (6 reads / 8 MFMA per K16-step) vs v5's 32768 —
// the acc-128 tier reached with only 24 transient regs (M8N4-16x16 needed 48 and spilled).
// conv1 phase + staging + dbuf identical to proven R10/R13 code.
__global__ __launch_bounds__(256) void fused_conv_kernel(const float* __restrict__ x,
                                                         const unsigned short* __restrict__ w1bf,
                                                         const float* __restrict__ b1,
                                                         const unsigned short* __restrict__ w2bf,
                                                         const float* __restrict__ b2,
                                                         float* __restrict__ partial)
{
    const int xt = blockIdx.x, yt = blockIdx.y, b = blockIdx.z;
    const int x0 = xt * 16, ty0 = yt * 16;
    const int tid = threadIdx.x;
    const int w = tid >> 6, lane = tid & 63;
    const int wp = w >> 1, wn = w & 1;      // conv2: px rows [wp*8,+8), oc [wn*64,+64)
    const int l15 = lane & 15, lq = lane >> 4;       // conv1 (16x16) indexing
    const int l31 = lane & 31, hi = lane >> 5;       // conv2 (32x32) indexing

    __shared__ char smem[74240];
    short* halo  = (short*)smem;                // [324 pos(18x18)][64 ic] XOR-swizzled, 41472 B
    char*  wlds0 = smem + 41472;                // tap dbuf slot 0, 16384 B
    char*  wlds1 = smem + 41472 + 16384;        // tap dbuf slot 1, 16384 B
    float* xpatch = (float*)wlds1;              // ALIAS: [3][20][20]=1200 + zero tail (1568 floats)

    // ---- phase 0a: stage tap-0 weights into wlds0 (async; drained by first barrier) ----
#pragma unroll
    for (int it = 0; it < 4; ++it) {
        int cbase = it * 256 + w * 64;
        int c = cbase + lane;
        int src = (c * 16) ^ (((c >> 3) & 7) << 4);
        gload_lds16((const char*)w2bf + src, wlds0 + cbase * 16);
    }

    // ---- phase 0b: stage x patch [3][20][20] (origin ty0-2, x0-2); zero tail for k>=27 ----
    for (int i = tid; i < 1568; i += 256) {
        float v = 0.f;
        if (i < 1200) {
            int ic = i / 400; int rem = i - ic * 400;
            int r = rem / 20, c = rem - r * 20;
            int gy = ty0 - 2 + r, gx = x0 - 2 + c;
            if (gy >= 0 && gy < HH && gx >= 0 && gx < WW)
                v = x[((b * 3 + ic) * HH + gy) * WW + gx];
        }
        xpatch[i] = v;
    }

    // conv1 constants (dead after phase 1)
    short8 aw[4];
#pragma unroll
    for (int f = 0; f < 4; f++)
        aw[f] = *(const short8*)(w1bf + (f * 16 + l15) * 32 + lq * 8);
    float bias1[4][4];
#pragma unroll
    for (int f = 0; f < 4; f++)
#pragma unroll
        for (int j = 0; j < 4; j++)
            bias1[f][j] = b1[f * 16 + lq * 4 + j];

    int koff[8];
#pragma unroll
    for (int j = 0; j < 8; j++) {
        int k = lq * 8 + j;
        int ic = (k >= 18) ? 2 : (k >= 9 ? 1 : 0);
        int t = k - ic * 9;
        int dy = (t >= 6) ? 2 : (t >= 3 ? 1 : 0);
        int dx = t - dy * 3;
        koff[j] = (k < 27) ? ((ic * 20 + dy) * 20 + dx) * 4 : 4800;  // zero tail
    }
    __syncthreads();   // xpatch + wlds0 ready

    // ---- phase 1: conv1 -> halo (21 px-groups of 16 over 324 halo px; R10-proven) ----
    const char* xpb = (const char*)xpatch;
    for (int g = w; g < 21; g += 4) {
        int px0 = g * 16 + l15;
        int px = px0 > 323 ? 323 : px0;
        int row = (px * 456) >> 13;       // px/18, exact for px<324
        int col = px - row * 18;
        int rofs = row * 80 + col * 4;

        float pv[8];
#pragma unroll
        for (int j = 0; j < 8; j++)
            pv[j] = *(const float*)(xpb + (koff[j] + rofs));
        short8 bp;
        unsigned int* bpu = (unsigned int*)&bp;
#pragma unroll
        for (int jj = 0; jj < 4; jj++)
            bpu[jj] = (unsigned int)f2bf(pv[2 * jj]) | ((unsigned int)f2bf(pv[2 * jj + 1]) << 16);

        int gy = ty0 + row - 1, gx = x0 + col - 1;
        float vm = (gy >= 0 && gy < HH && gx >= 0 && gx < WW) ? 1.f : 0.f;  // SAME-pad mask
        bool wr = (px0 < 324);

#pragma unroll
        for (int f = 0; f < 4; f++) {
            f32x4 c = __builtin_amdgcn_mfma_f32_16x16x32_bf16(aw[f], bp,
                        (f32x4){0.f, 0.f, 0.f, 0.f}, 0, 0, 0);
            float v0 = fmaxf(c[0] + bias1[f][0], 0.f) * vm;
            float v1 = fmaxf(c[1] + bias1[f][1], 0.f) * vm;
            float v2 = fmaxf(c[2] + bias1[f][2], 0.f) * vm;
            float v3 = fmaxf(c[3] + bias1[f][3], 0.f) * vm;
            if (wr) {
                u32x2 pk;
                pk.x = (unsigned int)f2bf(v0) | ((unsigned int)f2bf(v1) << 16);
                pk.y = (unsigned int)f2bf(v2) | ((unsigned int)f2bf(v3) << 16);
                int byte = (px * 128 + f * 32 + lq * 8) ^ ((px & 7) << 4);
                *(u32x2*)((char*)halo + byte) = pk;
            }
        }
    }
    __syncthreads();   // halo ready; xpatch now DEAD -> wlds1 alias becomes free

    // ---- phase 2: conv2 (32x32x16 MFMA, M4N2, weights from LDS dbuf, per-tap stage) ----
    f32x16 acc[4][2];
#pragma unroll
    for (int mf = 0; mf < 4; mf++)
#pragma unroll
        for (int nf = 0; nf < 2; nf++)
#pragma unroll
            for (int q = 0; q < 16; q++)
                acc[mf][nf][q] = 0.f;

#pragma unroll
    for (int t = 0; t < 9; ++t) {
        if (t < 8) {
            char* wdst = ((t + 1) & 1) ? wlds1 : wlds0;
#pragma unroll
            for (int it = 0; it < 4; ++it) {
                int cbase = it * 256 + w * 64;
                int c = cbase + lane;
                int src = (c * 16) ^ (((c >> 3) & 7) << 4);
                gload_lds16((const char*)w2bf + (t + 1) * 16384 + src, wdst + cbase * 16);
            }
        }
        const int dy = t / 3, dx = t % 3;
        const char* wbuf = (t & 1) ? wlds1 : wlds0;

#pragma unroll
        for (int s16 = 0; s16 < 4; s16++) {
            short8 bfr[2];
#pragma unroll
            for (int nf = 0; nf < 2; nf++) {
                int oc = wn * 64 + nf * 32 + l31;
                int byte = (oc * 128 + s16 * 32 + hi * 16) ^ ((oc & 7) << 4);
                bfr[nf] = *(const short8*)(wbuf + byte);
            }
            short8 a[4];
#pragma unroll
            for (int mf = 0; mf < 4; mf++) {
                int pos = (wp * 8 + mf * 2 + (l31 >> 4) + dy) * 18 + (l31 & 15) + dx;
                int byte = (pos * 128 + s16 * 32 + hi * 16) ^ ((pos & 7) << 4);
                a[mf] = *(const short8*)((const char*)halo + byte);
            }
#pragma unroll
            for (int mf = 0; mf < 4; mf++)
#pragma unroll
                for (int nf = 0; nf < 2; nf++)
                    acc[mf][nf] = __builtin_amdgcn_mfma_f32_32x32x16_bf16(a[mf], bfr[nf], acc[mf][nf], 0, 0, 0);
        }
        __syncthreads();   // drains stage(t+1); publishes the other wlds slot
    }

    // ---- phase 3: bias + relu + px-sum -> partial ----
    // C/D 32x32: col(oc)=lane&31, rows per lane = 16 of 32 (union over hi) -> sum regs + xor32.
    float s[2];
#pragma unroll
    for (int nf = 0; nf < 2; nf++) {
        float bias = b2[wn * 64 + nf * 32 + l31];
        float v = 0.f;
#pragma unroll
        for (int mf = 0; mf < 4; mf++)
#pragma unroll
            for (int q = 0; q < 16; q++)
                v += fmaxf(acc[mf][nf][q] + bias, 0.f);
        v += __shfl_xor(v, 32, 64);
        s[nf] = v;
    }

    float* red = (float*)halo;     // halo reads all complete (final K-loop barrier)
    if (hi == 0) {
#pragma unroll
        for (int nf = 0; nf < 2; nf++)
            red[((wp * 2 + wn) * 2 + nf) * 32 + l31] = s[nf];
    }
    __syncthreads();
    if (tid < 128) {
        int oc = tid;
        int wn2 = oc >> 6, nf2 = (oc >> 5) & 1, c32 = oc & 31;
        float tot = red[((0 * 2 + wn2) * 2 + nf2) * 32 + c32] +
                    red[((1 * 2 + wn2) * 2 + nf2) * 32 + c32];
        int tile = yt * 14 + xt;
        partial[((size_t)b * 128 + oc) * 196 + tile] = tot;
    }
}

// ---------------- feats: sum 196 tile-partials -> mean ----------------
__global__ void feats_reduce(const float* __restrict__ partial, float* __restrict__ out)
{
    int t = blockIdx.x;           // 0..4095 = b*128+oc
    int lane = threadIdx.x;       // 64
    float s = 0.f;
    for (int k = lane; k < 196; k += 64) s += partial[(size_t)t * 196 + k];
#pragma unroll
    for (int m = 32; m >= 1; m >>= 1) s += __shfl_xor(s, m, 64);
    if (lane == 0) out[t] = s * (1.f / 50176.f);
}

// ---------------- NMS: one block per batch (exact reference semantics) ----------------
__global__ __launch_bounds__(128) void nms_kernel(const float* __restrict__ boxes,
                                                  const float* __restrict__ scores,
                                                  float* __restrict__ out)
{
    const int b = blockIdx.x;
    const int tid = threadIdx.x;
    __shared__ float rs[100];
    __shared__ float bx1[100], by1[100], bx2[100], by2[100];
    __shared__ float ss[100], sx1[100], sy1[100], sx2[100], sy2[100], sarea[100];
    __shared__ int keep_s[100];

    if (tid < 100) {
        rs[tid] = scores[b * 100 + tid];
        bx1[tid] = boxes[(b * 100 + tid) * 4 + 0];
        by1[tid] = boxes[(b * 100 + tid) * 4 + 1];
        bx2[tid] = boxes[(b * 100 + tid) * 4 + 2];
        by2[tid] = boxes[(b * 100 + tid) * 4 + 3];
    }
    __syncthreads();
    if (tid < 100) {
        float s = rs[tid];
        int r = 0;
        for (int j = 0; j < 100; j++) {
            float sj = rs[j];
            r += (sj > s) || (sj == s && j < tid);  // stable descending rank
        }
        ss[r] = s; sx1[r] = bx1[tid]; sy1[r] = by1[tid];
        sx2[r] = bx2[tid]; sy2[r] = by2[tid];
        keep_s[tid] = 1;
    }
    __syncthreads();
    if (tid < 100)
        sarea[tid] = fmaxf(sx2[tid] - sx1[tid], 0.f) * fmaxf(sy2[tid] - sy1[tid], 0.f);
    __syncthreads();

    for (int i = 0; i < 99; i++) {
        if (keep_s[i] && tid > i && tid < 100) {
            float xx1 = fmaxf(sx1[i], sx1[tid]);
            float yy1 = fmaxf(sy1[i], sy1[tid]);
            float xx2 = fminf(sx2[i], sx2[tid]);
            float yy2 = fminf(sy2[i], sy2[tid]);
            float inter = fmaxf(xx2 - xx1, 0.f) * fmaxf(yy2 - yy1, 0.f);
            float iou = inter / (sarea[i] + sarea[tid] - inter + 1e-9f);
            if (iou > 0.5f) keep_s[tid] = 0;
        }
        __syncthreads();
    }

    if (tid < 100) {
        int k = keep_s[tid];
        int gi = b * 100 + tid;
        out[OUT_BOXES + gi * 4 + 0] = k ? sx1[tid] : 0.f;
        out[OUT_BOXES + gi * 4 + 1] = k ? sy1[tid] : 0.f;
        out[OUT_BOXES + gi * 4 + 2] = k ? sx2[tid] : 0.f;
        out[OUT_BOXES + gi * 4 + 3] = k ? sy2[tid] : 0.f;
        out[OUT_SCORES + gi] = k ? ss[tid] : 0.f;
        out[OUT_KEEP + gi] = k ? 1.f : 0.f;
    }
}

extern "C" void kernel_launch(void* const* d_in, const int* in_sizes, int n_in,
                              void* d_out, int out_size, void* d_ws, size_t ws_size,
                              hipStream_t stream)
{
    const float* x      = (const float*)d_in[0];
    const float* boxes  = (const float*)d_in[1];
    const float* scores = (const float*)d_in[2];
    const float* w1     = (const float*)d_in[3];
    const float* b1     = (const float*)d_in[4];
    const float* w2     = (const float*)d_in[5];
    const float* b2     = (const float*)d_in[6];
    float* out = (float*)d_out;

    // ws: w2bf (147 KB) | w1bf (4 KB) | partial (3.2 MB) — no h1 buffer
    char* wsb = (char*)d_ws;
    unsigned short* w2bf = (unsigned short*)wsb;
    unsigned short* w1bf = (unsigned short*)(wsb + 9 * 128 * 64 * 2);
    float*          partial = (float*)(wsb + 9 * 128 * 64 * 2 + 64 * 32 * 2);

    w2_convert<<<(9 * 128 * 64 + 255) / 256, 256, 0, stream>>>(w2, w2bf);
    w1_convert<<<8, 256, 0, stream>>>(w1, w1bf);

    fused_conv_kernel<<<dim3(14, 14, 32), 256, 0, stream>>>(x, w1bf, b1, w2bf, b2, partial);

    feats_reduce<<<4096, 64, 0, stream>>>(partial, out + OUT_FEATS);
    nms_kernel<<<32, 128, 0, stream>>>(boxes, scores, out);
}

// Round 21
// 264.882 us; speedup vs baseline: 1.3812x; 1.0114x over previous
//
#include <hip/hip_runtime.h>
#include <hip/hip_bf16.h>

#define HH 224
#define WW 224

// d_out layout (floats): feats[32*128] | final_boxes[32*100*4] | final_scores[32*100] | keep[32*100]
#define OUT_FEATS  0
#define OUT_BOXES  4096
#define OUT_SCORES 16896
#define OUT_KEEP   20096

typedef __attribute__((ext_vector_type(8))) short short8;
typedef __attribute__((ext_vector_type(4))) float f32x4;
typedef __attribute__((ext_vector_type(16))) float f32x16;
typedef __attribute__((ext_vector_type(4))) unsigned int u32x4;
typedef __attribute__((ext_vector_type(2))) unsigned int u32x2;

static __device__ __forceinline__ unsigned short f2bf(float f) {
    __hip_bfloat16 h = __float2bfloat16(f);
    return *(unsigned short*)&h;
}

static __device__ __forceinline__ void gload_lds16(const void* g, void* l) {
    __builtin_amdgcn_global_load_lds(
        (const __attribute__((address_space(1))) unsigned int*)g,
        (__attribute__((address_space(3))) unsigned int*)l, 16, 0, 0);
}

// ---------------- w2 (128,64,3,3) fp32 -> bf16 w2t[tap][kslot 8][oc 128][e 8], ic = kslot*8+e ----------------
// Global layout == linear LDS image: staging needs NO swizzle, conv2 B-reads are DENSE.
__global__ void w2_convert(const float* __restrict__ w2, unsigned short* __restrict__ w2t)
{
    int t = blockIdx.x * 256 + threadIdx.x;
    if (t >= 9 * 128 * 64) return;
    int e     = t & 7;
    int oc    = (t >> 3) & 127;
    int kslot = (t >> 10) & 7;
    int tap   = t >> 13;
    int ic    = kslot * 8 + e;
    w2t[t] = f2bf(w2[(oc * 64 + ic) * 9 + tap]);
}

// ---------------- w1 (64,3,3,3) fp32 -> bf16 [oc][k32], k=ic*9+dy*3+dx, pad 27..31=0 ----------------
__global__ void w1_convert(const float* __restrict__ w1, unsigned short* __restrict__ w1bf)
{
    int t = blockIdx.x * 256 + threadIdx.x;
    if (t >= 64 * 32) return;
    int oc = t >> 5, k = t & 31;
    unsigned short v = 0;
    if (k < 27) v = f2bf(w1[oc * 27 + k]);
    w1bf[t] = v;
}

// ================= FUSED conv1+conv2 per 16x16 output tile (v12: 32x32 MFMA + k-major LDS) =================
// v11 (268us best: 32x32 frags, acc=128 AGPR, 2 blocks/CU) with BOTH LDS layouts k-major:
//   halo[icslot 8][pos 324][16B]  (5184 B/slot) — A-read byte = kslot*5184 + pos*16  -> DENSE
//   wlds[kslot 8][oc 128][16B]    (2048 B/slot) — B-read byte = kslot*2048 + oc*16   -> DENSE
// Dense contiguous 16B-stride wave reads are bank-conflict-free; v11's 128B-row-stride
// reads were 4-way aliased (25.7M conflict cycles). No XOR swizzle anywhere.
__global__ __launch_bounds__(256) void fused_conv_kernel(const float* __restrict__ x,
                                                         const unsigned short* __restrict__ w1bf,
                                                         const float* __restrict__ b1,
                                                         const unsigned short* __restrict__ w2t,
                                                         const float* __restrict__ b2,
                                                         float* __restrict__ partial)
{
    const int xt = blockIdx.x, yt = blockIdx.y, b = blockIdx.z;
    const int x0 = xt * 16, ty0 = yt * 16;
    const int tid = threadIdx.x;
    const int w = tid >> 6, lane = tid & 63;
    const int wp = w >> 1, wn = w & 1;      // conv2: px rows [wp*8,+8), oc [wn*64,+64)
    const int l15 = lane & 15, lq = lane >> 4;       // conv1 (16x16) indexing
    const int l31 = lane & 31, hi = lane >> 5;       // conv2 (32x32) indexing

    __shared__ char smem[74240];
    char*  halo  = smem;                        // [icslot 8][324 pos][16B] = 41472 B
    char*  wlds0 = smem + 41472;                // tap dbuf slot 0, 16384 B
    char*  wlds1 = smem + 41472 + 16384;        // tap dbuf slot 1, 16384 B
    float* xpatch = (float*)wlds1;              // ALIAS: [3][20][20]=1200 + zero tail (1568 floats)

    // ---- phase 0a: stage tap-0 weights into wlds0 (async, LINEAR; drained by first barrier) ----
#pragma unroll
    for (int it = 0; it < 4; ++it) {
        int c = it * 256 + tid;
        gload_lds16((const char*)w2t + c * 16, wlds0 + c * 16);
    }

    // ---- phase 0b: stage x patch [3][20][20] (origin ty0-2, x0-2); zero tail for k>=27 ----
    for (int i = tid; i < 1568; i += 256) {
        float v = 0.f;
        if (i < 1200) {
            int ic = i / 400; int rem = i - ic * 400;
            int r = rem / 20, c = rem - r * 20;
            int gy = ty0 - 2 + r, gx = x0 - 2 + c;
            if (gy >= 0 && gy < HH && gx >= 0 && gx < WW)
                v = x[((b * 3 + ic) * HH + gy) * WW + gx];
        }
        xpatch[i] = v;
    }

    // conv1 constants (dead after phase 1)
    short8 aw[4];
#pragma unroll
    for (int f = 0; f < 4; f++)
        aw[f] = *(const short8*)(w1bf + (f * 16 + l15) * 32 + lq * 8);
    float bias1[4][4];
#pragma unroll
    for (int f = 0; f < 4; f++)
#pragma unroll
        for (int j = 0; j < 4; j++)
            bias1[f][j] = b1[f * 16 + lq * 4 + j];

    int koff[8];
#pragma unroll
    for (int j = 0; j < 8; j++) {
        int k = lq * 8 + j;
        int ic = (k >= 18) ? 2 : (k >= 9 ? 1 : 0);
        int t = k - ic * 9;
        int dy = (t >= 6) ? 2 : (t >= 3 ? 1 : 0);
        int dx = t - dy * 3;
        koff[j] = (k < 27) ? ((ic * 20 + dy) * 20 + dx) * 4 : 4800;  // zero tail
    }
    __syncthreads();   // xpatch + wlds0 ready

    // ---- phase 1: conv1 -> halo (21 px-groups of 16 over 324 halo px) ----
    // halo write: oc group f*16+lq*4 -> icslot = f*2+(lq>>1), byte = icslot*5184 + px*16 + (lq&1)*8
    const char* xpb = (const char*)xpatch;
    for (int g = w; g < 21; g += 4) {
        int px0 = g * 16 + l15;
        int px = px0 > 323 ? 323 : px0;
        int row = (px * 456) >> 13;       // px/18, exact for px<324
        int col = px - row * 18;
        int rofs = row * 80 + col * 4;

        float pv[8];
#pragma unroll
        for (int j = 0; j < 8; j++)
            pv[j] = *(const float*)(xpb + (koff[j] + rofs));
        short8 bp;
        unsigned int* bpu = (unsigned int*)&bp;
#pragma unroll
        for (int jj = 0; jj < 4; jj++)
            bpu[jj] = (unsigned int)f2bf(pv[2 * jj]) | ((unsigned int)f2bf(pv[2 * jj + 1]) << 16);

        int gy = ty0 + row - 1, gx = x0 + col - 1;
        float vm = (gy >= 0 && gy < HH && gx >= 0 && gx < WW) ? 1.f : 0.f;  // SAME-pad mask
        bool wr = (px0 < 324);

#pragma unroll
        for (int f = 0; f < 4; f++) {
            f32x4 c = __builtin_amdgcn_mfma_f32_16x16x32_bf16(aw[f], bp,
                        (f32x4){0.f, 0.f, 0.f, 0.f}, 0, 0, 0);
            float v0 = fmaxf(c[0] + bias1[f][0], 0.f) * vm;
            float v1 = fmaxf(c[1] + bias1[f][1], 0.f) * vm;
            float v2 = fmaxf(c[2] + bias1[f][2], 0.f) * vm;
            float v3 = fmaxf(c[3] + bias1[f][3], 0.f) * vm;
            if (wr) {
                u32x2 pk;
                pk.x = (unsigned int)f2bf(v0) | ((unsigned int)f2bf(v1) << 16);
                pk.y = (unsigned int)f2bf(v2) | ((unsigned int)f2bf(v3) << 16);
                int byte = (f * 2 + (lq >> 1)) * 5184 + px * 16 + (lq & 1) * 8;
                *(u32x2*)(halo + byte) = pk;
            }
        }
    }
    __syncthreads();   // halo ready; xpatch now DEAD -> wlds1 alias becomes free

    // ---- phase 2: conv2 (32x32x16 MFMA, M4N2, k-major dense LDS reads) ----
    f32x16 acc[4][2];
#pragma unroll
    for (int mf = 0; mf < 4; mf++)
#pragma unroll
        for (int nf = 0; nf < 2; nf++)
#pragma unroll
            for (int q = 0; q < 16; q++)
                acc[mf][nf][q] = 0.f;

#pragma unroll
    for (int t = 0; t < 9; ++t) {
        if (t < 8) {
            char* wdst = ((t + 1) & 1) ? wlds1 : wlds0;
            const char* wsrc = (const char*)w2t + (t + 1) * 16384;
#pragma unroll
            for (int it = 0; it < 4; ++it) {
                int c = it * 256 + tid;
                gload_lds16(wsrc + c * 16, wdst + c * 16);
            }
        }
        const int dy = t / 3, dx = t % 3;
        const char* wbuf = (t & 1) ? wlds1 : wlds0;

#pragma unroll
        for (int s16 = 0; s16 < 4; s16++) {
            const int kslot = s16 * 2 + hi;
            short8 bfr[2];
#pragma unroll
            for (int nf = 0; nf < 2; nf++) {
                int oc = wn * 64 + nf * 32 + l31;
                bfr[nf] = *(const short8*)(wbuf + kslot * 2048 + oc * 16);
            }
            short8 a[4];
#pragma unroll
            for (int mf = 0; mf < 4; mf++) {
                int pos = (wp * 8 + mf * 2 + (l31 >> 4) + dy) * 18 + (l31 & 15) + dx;
                a[mf] = *(const short8*)(halo + kslot * 5184 + pos * 16);
            }
#pragma unroll
            for (int mf = 0; mf < 4; mf++)
#pragma unroll
                for (int nf = 0; nf < 2; nf++)
                    acc[mf][nf] = __builtin_amdgcn_mfma_f32_32x32x16_bf16(a[mf], bfr[nf], acc[mf][nf], 0, 0, 0);
        }
        __syncthreads();   // drains stage(t+1); publishes the other wlds slot
    }

    // ---- phase 3: bias + relu + px-sum -> partial ----
    // C/D 32x32: col(oc)=lane&31 -> sum 16 regs + xor32 unions the px rows.
    float s[2];
#pragma unroll
    for (int nf = 0; nf < 2; nf++) {
        float bias = b2[wn * 64 + nf * 32 + l31];
        float v = 0.f;
#pragma unroll
        for (int mf = 0; mf < 4; mf++)
#pragma unroll
            for (int q = 0; q < 16; q++)
                v += fmaxf(acc[mf][nf][q] + bias, 0.f);
        v += __shfl_xor(v, 32, 64);
        s[nf] = v;
    }

    float* red = (float*)halo;     // halo reads all complete (final K-loop barrier)
    if (hi == 0) {
#pragma unroll
        for (int nf = 0; nf < 2; nf++)
            red[((wp * 2 + wn) * 2 + nf) * 32 + l31] = s[nf];
    }
    __syncthreads();
    if (tid < 128) {
        int oc = tid;
        int wn2 = oc >> 6, nf2 = (oc >> 5) & 1, c32 = oc & 31;
        float tot = red[((0 * 2 + wn2) * 2 + nf2) * 32 + c32] +
                    red[((1 * 2 + wn2) * 2 + nf2) * 32 + c32];
        int tile = yt * 14 + xt;
        partial[((size_t)b * 128 + oc) * 196 + tile] = tot;
    }
}

// ---------------- feats: sum 196 tile-partials -> mean ----------------
__global__ void feats_reduce(const float* __restrict__ partial, float* __restrict__ out)
{
    int t = blockIdx.x;           // 0..4095 = b*128+oc
    int lane = threadIdx.x;       // 64
    float s = 0.f;
    for (int k = lane; k < 196; k += 64) s += partial[(size_t)t * 196 + k];
#pragma unroll
    for (int m = 32; m >= 1; m >>= 1) s += __shfl_xor(s, m, 64);
    if (lane == 0) out[t] = s * (1.f / 50176.f);
}

// ---------------- NMS: one block per batch (exact reference semantics) ----------------
__global__ __launch_bounds__(128) void nms_kernel(const float* __restrict__ boxes,
                                                  const float* __restrict__ scores,
                                                  float* __restrict__ out)
{
    const int b = blockIdx.x;
    const int tid = threadIdx.x;
    __shared__ float rs[100];
    __shared__ float bx1[100], by1[100], bx2[100], by2[100];
    __shared__ float ss[100], sx1[100], sy1[100], sx2[100], sy2[100], sarea[100];
    __shared__ int keep_s[100];

    if (tid < 100) {
        rs[tid] = scores[b * 100 + tid];
        bx1[tid] = boxes[(b * 100 + tid) * 4 + 0];
        by1[tid] = boxes[(b * 100 + tid) * 4 + 1];
        bx2[tid] = boxes[(b * 100 + tid) * 4 + 2];
        by2[tid] = boxes[(b * 100 + tid) * 4 + 3];
    }
    __syncthreads();
    if (tid < 100) {
        float s = rs[tid];
        int r = 0;
        for (int j = 0; j < 100; j++) {
            float sj = rs[j];
            r += (sj > s) || (sj == s && j < tid);  // stable descending rank
        }
        ss[r] = s; sx1[r] = bx1[tid]; sy1[r] = by1[tid];
        sx2[r] = bx2[tid]; sy2[r] = by2[tid];
        keep_s[tid] = 1;
    }
    __syncthreads();
    if (tid < 100)
        sarea[tid] = fmaxf(sx2[tid] - sx1[tid], 0.f) * fmaxf(sy2[tid] - sy1[tid], 0.f);
    __syncthreads();

    for (int i = 0; i < 99; i++) {
        if (keep_s[i] && tid > i && tid < 100) {
            float xx1 = fmaxf(sx1[i], sx1[tid]);
            float yy1 = fmaxf(sy1[i], sy1[tid]);
            float xx2 = fminf(sx2[i], sx2[tid]);
            float yy2 = fminf(sy2[i], sy2[tid]);
            float inter = fmaxf(xx2 - xx1, 0.f) * fmaxf(yy2 - yy1, 0.f);
            float iou = inter / (sarea[i] + sarea[tid] - inter + 1e-9f);
            if (iou > 0.5f) keep_s[tid] = 0;
        }
        __syncthreads();
    }

    if (tid < 100) {
        int k = keep_s[tid];
        int gi = b * 100 + tid;
        out[OUT_BOXES + gi * 4 + 0] = k ? sx1[tid] : 0.f;
        out[OUT_BOXES + gi * 4 + 1] = k ? sy1[tid] : 0.f;
        out[OUT_BOXES + gi * 4 + 2] = k ? sx2[tid] : 0.f;
        out[OUT_BOXES + gi * 4 + 3] = k ? sy2[tid] : 0.f;
        out[OUT_SCORES + gi] = k ? ss[tid] : 0.f;
        out[OUT_KEEP + gi] = k ? 1.f : 0.f;
    }
}

extern "C" void kernel_launch(void* const* d_in, const int* in_sizes, int n_in,
                              void* d_out, int out_size, void* d_ws, size_t ws_size,
                              hipStream_t stream)
{
    const float* x      = (const float*)d_in[0];
    const float* boxes  = (const float*)d_in[1];
    const float* scores = (const float*)d_in[2];
    const float* w1     = (const float*)d_in[3];
    const float* b1     = (const float*)d_in[4];
    const float* w2     = (const float*)d_in[5];
    const float* b2     = (const float*)d_in[6];
    float* out = (float*)d_out;

    // ws: w2t (147 KB) | w1bf (4 KB) | partial (3.2 MB) — no h1 buffer
    char* wsb = (char*)d_ws;
    unsigned short* w2t  = (unsigned short*)wsb;
    unsigned short* w1bf = (unsigned short*)(wsb + 9 * 128 * 64 * 2);
    float*          partial = (float*)(wsb + 9 * 128 * 64 * 2 + 64 * 32 * 2);

    w2_convert<<<(9 * 128 * 64 + 255) / 256, 256, 0, stream>>>(w2, w2t);
    w1_convert<<<8, 256, 0, stream>>>(w1, w1bf);

    fused_conv_kernel<<<dim3(14, 14, 32), 256, 0, stream>>>(x, w1bf, b1, w2t, b2, partial);

    feats_reduce<<<4096, 64, 0, stream>>>(partial, out + OUT_FEATS);
    nms_kernel<<<32, 128, 0, stream>>>(boxes, scores, out);
}